// Round 8
// baseline (581.157 us; speedup 1.0000x reference)
//
#include <hip/hip_runtime.h>
#include <hip/hip_bf16.h>

// Problem constants
#define NB 8
#define NS 8
#define NT 256
#define ND 256
#define NH 8
#define NDK 64
#define NHD 512
#define NL 2
#define NF 256
#define NR 512
#define NM 128
#define NTOK 16384   // B*S*T
#define NROW 1024    // B*M

typedef __attribute__((ext_vector_type(8))) short short8;
typedef __attribute__((ext_vector_type(4))) float f32x4;

__device__ __forceinline__ unsigned short f2bf(float x) {
    unsigned u = __builtin_bit_cast(unsigned, x);
    unsigned r = (u + 0x7fffu + ((u >> 16) & 1u)) >> 16;
    return (unsigned short)r;
}
__device__ __forceinline__ float bf2f(unsigned short x) {
    return __builtin_bit_cast(float, ((unsigned)x) << 16);
}
__device__ __forceinline__ float wred(float v) {
#pragma unroll
    for (int o = 32; o > 0; o >>= 1) v += __shfl_xor(v, o, 64);
    return v;
}

// ---------------------------------------------------------------------------
// Grid barrier for 256 co-resident blocks (1 block/CU, no LDS).  Device-scope
// release on arrive + acquire after spin handles cross-XCD L2 (G16).
// Counter zeroed by prep_all each call (d_ws re-poisoned between launches).
// ---------------------------------------------------------------------------
__device__ __forceinline__ void gridbar(unsigned* c) {
    __syncthreads();
    if (threadIdx.x == 0) {
        __hip_atomic_fetch_add(c, 1u, __ATOMIC_RELEASE, __HIP_MEMORY_SCOPE_AGENT);
        while (__hip_atomic_load(c, __ATOMIC_RELAXED, __HIP_MEMORY_SCOPE_AGENT) < 256u)
            __builtin_amdgcn_s_sleep(16);
        (void)__hip_atomic_load(c, __ATOMIC_ACQUIRE, __HIP_MEMORY_SCOPE_AGENT);
    }
    __syncthreads();
}

// ---------------------------------------------------------------------------
// Merged prep kernel.  Grid 1648 blocks:
//  [0,512):    encoded fp32 -> XF bf16 fragment-major (32-token LDS transpose)
//  [512,1280): head weights -> WP fragment-major images + W1L
//  [1280,1648): ds/ff/de weights -> WG fragment-major images (B-orientation)
// Block 0 additionally zeroes the tail barrier counters.
// ---------------------------------------------------------------------------
__global__ __launch_bounds__(256) void prep_all(
    const float* __restrict__ enc,
    const float* __restrict__ kW1, const float* __restrict__ kW2, const float* __restrict__ kW3,
    const float* __restrict__ vW1, const float* __restrict__ vW2, const float* __restrict__ vW3,
    const float* __restrict__ dsW, const float* __restrict__ ffW1,
    const float* __restrict__ ffW2, const float* __restrict__ deW1,
    const float* __restrict__ deW2, const float* __restrict__ deW3,
    unsigned short* __restrict__ XF, unsigned short* __restrict__ WP,
    float* __restrict__ W1L, unsigned short* __restrict__ WG,
    unsigned* __restrict__ BAR) {
    __shared__ float T[32][257];
    int bid = blockIdx.x, tid = threadIdx.x;
    if (bid == 0 && tid < 16) BAR[tid] = 0;
    if (bid < 512) {
        int t0 = bid * 32;
        const float* src = enc + (size_t)t0 * 256;
#pragma unroll
        for (int it = 0; it < 8; ++it) {
            int f4 = it * 256 + tid;
            int row = f4 >> 6, c = (f4 & 63) * 4;
            float4 v = *(const float4*)(src + row * 256 + c);
            T[row][c] = v.x; T[row][c + 1] = v.y; T[row][c + 2] = v.z; T[row][c + 3] = v.w;
        }
        __syncthreads();
        int tile = t0 >> 7, g = (t0 >> 6) & 1, nt0 = (t0 >> 4) & 3;
#pragma unroll
        for (int i = 0; i < 32; i += 8) {
            int o = tid * 32 + i;
            int lane = (o >> 3) & 63, ntp = (o >> 9) & 1, kc = o >> 10;
            int id = lane & 15, quad = lane >> 4;
            __align__(16) unsigned short p[8];
#pragma unroll
            for (int j = 0; j < 8; ++j) p[j] = f2bf(T[ntp * 16 + id][kc * 32 + quad * 8 + j]);
            size_t dsto = ((size_t)((((tile * 8 + kc) * 2 + g) * 4 + (nt0 + ntp)) * 64 + lane)) * 8;
            *(uint4*)(XF + dsto) = *(uint4*)p;
        }
    } else if (bid < 1280) {
        int lb = bid - 512;
        int combo = lb / 24, r = lb % 24;
        int st = r >> 3, kc = r & 7;
        int kvv = combo >> 4, l = (combo >> 3) & 1, h = combo & 7;
        unsigned short* dstc = WP + (size_t)combo * 147456;
        if (st < 2) {
            const float* W = (st == 0) ? (kvv ? vW1 : kW1) : (kvv ? vW2 : kW2);
            int rows = (st == 0) ? 257 : 256;
            const float* src = W + ((size_t)(l * 8 + h) * rows + kc * 32) * 256;
#pragma unroll
            for (int it = 0; it < 8; ++it) {
                int f4 = it * 256 + tid;
                int row = f4 >> 6, c = (f4 & 63) * 4;
                float4 v = *(const float4*)(src + (size_t)row * 256 + c);
                T[row][c] = v.x; T[row][c + 1] = v.y; T[row][c + 2] = v.z; T[row][c + 3] = v.w;
            }
            __syncthreads();
            unsigned short* dst = dstc + st * 65536 + kc * 8192;
#pragma unroll
            for (int i = 0; i < 32; i += 8) {
                int o = tid * 32 + i;
                int lane = (o >> 3) & 63, ftile = o >> 9;
                int id = lane & 15, quad = lane >> 4;
                __align__(16) unsigned short p[8];
#pragma unroll
                for (int j = 0; j < 8; ++j) p[j] = f2bf(T[quad * 8 + j][ftile * 16 + id]);
                *(uint4*)(dst + o) = *(uint4*)p;
            }
            if (st == 0 && kc == 0) {
                const float* hw = (kvv ? vW1 : kW1) + (size_t)(l * 8 + h) * 257 * 256;
                W1L[combo * 256 + tid] = hw[65536 + tid];
            }
        } else {
            const float* src = (kvv ? vW3 : kW3) + ((size_t)(l * 8 + h) * 256 + kc * 32) * 64;
#pragma unroll
            for (int it = 0; it < 2; ++it) {
                int f4 = it * 256 + tid;
                int row = f4 >> 4, c = (f4 & 15) * 4;
                float4 v = *(const float4*)(src + (size_t)row * 64 + c);
                T[row][c] = v.x; T[row][c + 1] = v.y; T[row][c + 2] = v.z; T[row][c + 3] = v.w;
            }
            __syncthreads();
            unsigned short* dst = dstc + 131072 + kc * 2048;
            int o = tid * 8;
            int lane = tid & 63, ftile = tid >> 6;
            int id = lane & 15, quad = lane >> 4;
            __align__(16) unsigned short p[8];
#pragma unroll
            for (int j = 0; j < 8; ++j) p[j] = f2bf(T[quad * 8 + j][ftile * 16 + id]);
            *(uint4*)(dst + o) = *(uint4*)p;
        }
    } else {
        int lb0 = bid - 1280;
        const float* src; int N, kc, ng; size_t base;
        if (lb0 < 32)       { int lb = lb0;       src = dsW;           N = 512; base = 0;       kc = lb >> 2; ng = lb & 3; }
        else if (lb0 < 96)  { int lb = lb0 - 32;  src = ffW1;          N = 512; base = 131072;  kc = lb >> 2; ng = lb & 3; }
        else if (lb0 < 160) { int lb = lb0 - 96;  src = ffW1 + 262144; N = 512; base = 393216;  kc = lb >> 2; ng = lb & 3; }
        else if (lb0 < 224) { int lb = lb0 - 160; src = ffW2;          N = 512; base = 655360;  kc = lb >> 2; ng = lb & 3; }
        else if (lb0 < 288) { int lb = lb0 - 224; src = ffW2 + 262144; N = 512; base = 917504;  kc = lb >> 2; ng = lb & 3; }
        else if (lb0 < 320) { int lb = lb0 - 288; src = deW1;          N = 256; base = 1179648; kc = lb >> 1; ng = lb & 1; }
        else if (lb0 < 336) { int lb = lb0 - 320; src = deW2;          N = 256; base = 1310720; kc = lb >> 1; ng = lb & 1; }
        else                { int lb = lb0 - 336; src = deW3;          N = 512; base = 1376256; kc = lb >> 2; ng = lb & 3; }
        int NTl = N >> 4;
        const float* s = src + (size_t)(kc * 32) * N + ng * 128;
#pragma unroll
        for (int it = 0; it < 4; ++it) {
            int f4 = it * 256 + tid;
            int row = f4 >> 5, c = (f4 & 31) * 4;
            float4 v = *(const float4*)(s + (size_t)row * N + c);
            T[row][c] = v.x; T[row][c + 1] = v.y; T[row][c + 2] = v.z; T[row][c + 3] = v.w;
        }
        __syncthreads();
        unsigned short* d = WG + base + (size_t)(kc * NTl + ng * 8) * 512;
#pragma unroll
        for (int i = 0; i < 16; i += 8) {
            int o = tid * 16 + i;
            int lane = (o >> 3) & 63, ntl = o >> 9;
            int id = lane & 15, quad = lane >> 4;
            __align__(16) unsigned short p[8];
#pragma unroll
            for (int j = 0; j < 8; ++j) p[j] = f2bf(T[quad * 8 + j][ntl * 16 + id]);
            *(uint4*)(d + o) = *(uint4*)p;
        }
    }
}

// ---------------------------------------------------------------------------
// Fused per-head MLP v7 (unchanged from R7): tile-major grid, combo-major KV,
// 2-deep W prefetch, 64-token tiles, 4 blocks/CU.
// ---------------------------------------------------------------------------
__global__ __launch_bounds__(256, 4) void heads_mlp(
    const float* __restrict__ tu, const unsigned short* __restrict__ XF,
    const unsigned short* __restrict__ WP, const float* __restrict__ W1L,
    const float* __restrict__ kb1, const float* __restrict__ kb2, const float* __restrict__ kb3,
    const float* __restrict__ vb1, const float* __restrict__ vb2, const float* __restrict__ vb3,
    unsigned short* __restrict__ KV) {
    __shared__ __align__(16) unsigned short smem[16896];   // 33792 B

    const int tid = threadIdx.x;
    const int w2 = tid >> 6, lane = tid & 63, id = lane & 15, quad = lane >> 4;
    const int combo = blockIdx.x & 31, t64 = blockIdx.x >> 5;
    const int kvv = combo >> 4, l = (combo >> 3) & 1, h = combo & 7;
    const int r0 = t64 * 64;
    const int tile128 = t64 >> 1, g = t64 & 1;
    const unsigned short* WF1 = WP + (size_t)combo * 147456;
    const unsigned short* WF2 = WF1 + 65536;
    const unsigned short* WF3 = WF1 + 131072;
    const float* b1 = (kvv ? vb1 : kb1) + (l * 8 + h) * 256;
    const float* b2 = (kvv ? vb2 : kb2) + (l * 8 + h) * 256;
    const float* b3 = (kvv ? vb3 : kb3) + (l * 8 + h) * 64;

    short8 afb[2][4];
#pragma unroll
    for (int ft = 0; ft < 4; ++ft) {
        afb[0][ft] = *(const short8*)(WF1 + (size_t)((w2 * 4 + ft) * 64 + lane) * 8);
        afb[1][ft] = *(const short8*)(WF1 + (size_t)((16 + w2 * 4 + ft) * 64 + lane) * 8);
    }
    {
        const uint4* s = (const uint4*)(XF + (size_t)tile128 * 32768 + g * 2048);
        uint4* d = (uint4*)smem;
#pragma unroll
        for (int kc = 0; kc < 8; ++kc) d[kc * 256 + tid] = s[kc * 512 + tid];
    }
    __syncthreads();

    f32x4 acc[4][4];
#pragma unroll
    for (int i = 0; i < 4; ++i)
#pragma unroll
        for (int j = 0; j < 4; ++j) acc[i][j] = (f32x4){0.f, 0.f, 0.f, 0.f};

    // stage 1
    {
#pragma unroll
        for (int kc = 0; kc < 8; ++kc) {
            short8 tn[4];
            if (kc + 2 < 8) {
#pragma unroll
                for (int ft = 0; ft < 4; ++ft)
                    tn[ft] = *(const short8*)(WF1 + (size_t)(((kc + 2) * 16 + w2 * 4 + ft) * 64 + lane) * 8);
            }
            short8 bf[4];
#pragma unroll
            for (int nt = 0; nt < 4; ++nt)
                bf[nt] = *(const short8*)(smem + (size_t)(kc * 4 + nt) * 512 + lane * 8);
#pragma unroll
            for (int ft = 0; ft < 4; ++ft)
#pragma unroll
                for (int nt = 0; nt < 4; ++nt)
                    acc[ft][nt] = __builtin_amdgcn_mfma_f32_16x16x32_bf16(afb[kc & 1][ft], bf[nt], acc[ft][nt], 0, 0, 0);
            if (kc + 2 < 8) {
#pragma unroll
                for (int ft = 0; ft < 4; ++ft) afb[kc & 1][ft] = tn[ft];
            }
        }
    }
    __syncthreads();
    {
        float ur[4];
#pragma unroll
        for (int nt = 0; nt < 4; ++nt) ur[nt] = tu[r0 + nt * 16 + id];
#pragma unroll
        for (int ft = 0; ft < 4; ++ft) {
            int fb = w2 * 64 + ft * 16 + quad * 4;
            float4 bb = *(const float4*)(b1 + fb);
            float4 wl = *(const float4*)(W1L + combo * 256 + fb);
            const float* bbp = (const float*)&bb;
            const float* wlp = (const float*)&wl;
#pragma unroll
            for (int nt = 0; nt < 4; ++nt) {
                unsigned short p[4];
#pragma unroll
                for (int r = 0; r < 4; ++r) {
                    float v = acc[ft][nt][r] + bbp[r] + ur[nt] * wlp[r];
                    p[r] = f2bf(fmaxf(v, 0.f));
                }
                uint2 pk;
                pk.x = (unsigned)p[0] | ((unsigned)p[1] << 16);
                pk.y = (unsigned)p[2] | ((unsigned)p[3] << 16);
                *(uint2*)(smem + (size_t)(nt * 16 + id) * 264 + fb) = pk;
            }
        }
    }
    __syncthreads();

    // stage 2
#pragma unroll
    for (int i = 0; i < 4; ++i)
#pragma unroll
        for (int j = 0; j < 4; ++j) acc[i][j] = (f32x4){0.f, 0.f, 0.f, 0.f};
    {
#pragma unroll
        for (int ft = 0; ft < 4; ++ft) {
            afb[0][ft] = *(const short8*)(WF2 + (size_t)((w2 * 4 + ft) * 64 + lane) * 8);
            afb[1][ft] = *(const short8*)(WF2 + (size_t)((16 + w2 * 4 + ft) * 64 + lane) * 8);
        }
#pragma unroll
        for (int kc = 0; kc < 8; ++kc) {
            short8 tn[4];
            if (kc + 2 < 8) {
#pragma unroll
                for (int ft = 0; ft < 4; ++ft)
                    tn[ft] = *(const short8*)(WF2 + (size_t)(((kc + 2) * 16 + w2 * 4 + ft) * 64 + lane) * 8);
            }
            short8 bf[4];
#pragma unroll
            for (int nt = 0; nt < 4; ++nt)
                bf[nt] = *(const short8*)(smem + (size_t)(nt * 16 + id) * 264 + kc * 32 + quad * 8);
#pragma unroll
            for (int ft = 0; ft < 4; ++ft)
#pragma unroll
                for (int nt = 0; nt < 4; ++nt)
                    acc[ft][nt] = __builtin_amdgcn_mfma_f32_16x16x32_bf16(afb[kc & 1][ft], bf[nt], acc[ft][nt], 0, 0, 0);
            if (kc + 2 < 8) {
#pragma unroll
                for (int ft = 0; ft < 4; ++ft) afb[kc & 1][ft] = tn[ft];
            }
        }
    }
    __syncthreads();
#pragma unroll
    for (int ft = 0; ft < 4; ++ft) {
        int fb = w2 * 64 + ft * 16 + quad * 4;
        float4 bb = *(const float4*)(b2 + fb);
        const float* bbp = (const float*)&bb;
#pragma unroll
        for (int nt = 0; nt < 4; ++nt) {
            unsigned short p[4];
#pragma unroll
            for (int r = 0; r < 4; ++r)
                p[r] = f2bf(fmaxf(acc[ft][nt][r] + bbp[r], 0.f));
            uint2 pk;
            pk.x = (unsigned)p[0] | ((unsigned)p[1] << 16);
            pk.y = (unsigned)p[2] | ((unsigned)p[3] << 16);
            *(uint2*)(smem + (size_t)(nt * 16 + id) * 264 + fb) = pk;
        }
    }
    __syncthreads();

    // stage 3
    f32x4 a3[4];
#pragma unroll
    for (int i = 0; i < 4; ++i) a3[i] = (f32x4){0.f, 0.f, 0.f, 0.f};
    {
        short8 af3[4], af3n[4];
#pragma unroll
        for (int ft = 0; ft < 4; ++ft)
            af3[ft] = *(const short8*)(WF3 + (size_t)(ft * 64 + lane) * 8);
#pragma unroll
        for (int kc = 0; kc < 8; ++kc) {
            if (kc < 7) {
#pragma unroll
                for (int ft = 0; ft < 4; ++ft)
                    af3n[ft] = *(const short8*)(WF3 + (size_t)(((kc + 1) * 4 + ft) * 64 + lane) * 8);
            }
            short8 b3f = *(const short8*)(smem + (size_t)(w2 * 16 + id) * 264 + kc * 32 + quad * 8);
#pragma unroll
            for (int ft = 0; ft < 4; ++ft)
                a3[ft] = __builtin_amdgcn_mfma_f32_16x16x32_bf16(af3[ft], b3f, a3[ft], 0, 0, 0);
#pragma unroll
            for (int ft = 0; ft < 4; ++ft) af3[ft] = af3n[ft];
        }
    }
    __syncthreads();
    {
        int tl = w2 * 16 + id;
#pragma unroll
        for (int ft = 0; ft < 4; ++ft) {
            int dk0 = ft * 16 + quad * 4;
            float4 bb = *(const float4*)(b3 + dk0);
            const float* bbp = (const float*)&bb;
            unsigned short p[4];
#pragma unroll
            for (int r = 0; r < 4; ++r) p[r] = f2bf(a3[ft][r] + bbp[r]);
            uint2 pk;
            pk.x = (unsigned)p[0] | ((unsigned)p[1] << 16);
            pk.y = (unsigned)p[2] | ((unsigned)p[3] << 16);
            *(uint2*)(smem + (size_t)tl * 72 + dk0) = pk;
        }
    }
    __syncthreads();
    {
#pragma unroll
        for (int it = 0; it < 2; ++it) {
            int tl = it * 32 + (tid >> 3), part = tid & 7;
            uint4 v = *(const uint4*)(smem + (size_t)tl * 72 + part * 8);
            size_t base = ((size_t)combo << 20) + (size_t)(r0 + tl) * 64 + part * 8;
            *(uint4*)(KV + base) = v;
        }
    }
}

// ---------------------------------------------------------------------------
// Device helper: bf16 gemm tile (1-deep prefetch), block role (bx, by).
// out = [relu](A[.xK]bf16 @ WF + bias [+ res_f32]); wave = 1 ntile x 2 mtiles.
// ---------------------------------------------------------------------------
__device__ __forceinline__ void gemm_stage(
    const unsigned short* __restrict__ A, const unsigned short* __restrict__ WF,
    const float* __restrict__ bias, const float* __restrict__ res,
    float* __restrict__ outf, unsigned short* __restrict__ outb,
    int K, int N, int relu, int bx, int by) {
    int tid = threadIdx.x, wv = tid >> 6, lane = tid & 63;
    int id = lane & 15, quad = lane >> 4;
    int ntile = bx * 4 + wv;
    int n0 = ntile * 16, m0 = by * 32;
    int NTl = N >> 4, KC = K >> 5;
    f32x4 acc0 = (f32x4){0.f, 0.f, 0.f, 0.f};
    f32x4 acc1 = (f32x4){0.f, 0.f, 0.f, 0.f};
    short8 bw = *(const short8*)(WF + (size_t)(ntile * 64 + lane) * 8);
    short8 a0 = *(const short8*)(A + (size_t)(m0 + id) * K + quad * 8);
    short8 a1 = *(const short8*)(A + (size_t)(m0 + 16 + id) * K + quad * 8);
    for (int kc = 0; kc < KC; ++kc) {
        short8 bwn, a0n, a1n;
        if (kc + 1 < KC) {
            bwn = *(const short8*)(WF + (size_t)(((kc + 1) * NTl + ntile) * 64 + lane) * 8);
            a0n = *(const short8*)(A + (size_t)(m0 + id) * K + (kc + 1) * 32 + quad * 8);
            a1n = *(const short8*)(A + (size_t)(m0 + 16 + id) * K + (kc + 1) * 32 + quad * 8);
        }
        acc0 = __builtin_amdgcn_mfma_f32_16x16x32_bf16(a0, bw, acc0, 0, 0, 0);
        acc1 = __builtin_amdgcn_mfma_f32_16x16x32_bf16(a1, bw, acc1, 0, 0, 0);
        bw = bwn; a0 = a0n; a1 = a1n;
    }
    float bv = bias[n0 + id];
#pragma unroll
    for (int mt = 0; mt < 2; ++mt) {
        f32x4 av = mt ? acc1 : acc0;
#pragma unroll
        for (int r = 0; r < 4; ++r) {
            int row = m0 + mt * 16 + quad * 4 + r;
            int n = n0 + id;
            float v = av[r] + bv;
            if (res) v += res[(size_t)row * N + n];
            if (relu) v = fmaxf(v, 0.f);
            if (outf) outf[(size_t)row * N + n] = v;
            if (outb) outb[(size_t)row * N + n] = f2bf(v);
        }
    }
}

// ---------------------------------------------------------------------------
// Fused tail: ONE kernel, 256 blocks x 256 thr (1 block/CU, no LDS), stages
// separated by grid barriers:
//  A: ds gemm (gather)  -> ATTV
//  per layer: B attn+LN1 -> XBUF/XBUFB ; C FF1 -> FBUFB ; D FF2+res -> YBUF ;
//             E LN2 -> ATTV/ATTVB
//  F de1 -> XBUFB ; G de2 -> FBUFB ; H de3 -> out
// ---------------------------------------------------------------------------
__global__ __launch_bounds__(256) void tail_fused(
    const float* __restrict__ enc, const int* __restrict__ mid,
    const int* __restrict__ left, const int* __restrict__ right,
    const int* __restrict__ ip,
    const unsigned short* __restrict__ KV, const unsigned short* __restrict__ WG,
    const float* __restrict__ ds_b,
    const float* __restrict__ ln1_g, const float* __restrict__ ln1_b,
    const float* __restrict__ ln2_g, const float* __restrict__ ln2_b,
    const float* __restrict__ ffb1, const float* __restrict__ ffb2,
    const float* __restrict__ deb1, const float* __restrict__ deb2,
    const float* __restrict__ deb3,
    float* __restrict__ ATTV, float* __restrict__ XBUF, float* __restrict__ YBUF,
    unsigned short* __restrict__ ATTVB, unsigned short* __restrict__ XBUFB,
    unsigned short* __restrict__ FBUFB,
    float* __restrict__ out, unsigned* __restrict__ BAR) {
    const int bid = blockIdx.x;
    const int tid = threadIdx.x;
    const int wv = tid >> 6, lane = tid & 63, id = lane & 15, quad = lane >> 4;
    const int iv = ip[0];

    // ---------------- stage A: ds gemm with gather ----------------
    {
        int bx = bid & 7, by = bid >> 3;
        int ntile = bx * 4 + wv;
        int n0 = ntile * 16, m0 = by * 32;
        int r0 = m0 + id, r1 = m0 + 16 + id;
        const float* a0p = enc + (((size_t)((r0 >> 7) * 8 + iv)) * 256 + mid[r0 & 127]) * 256 + quad * 8;
        const float* a1p = enc + (((size_t)((r1 >> 7) * 8 + iv)) * 256 + mid[r1 & 127]) * 256 + quad * 8;
        f32x4 acc0 = (f32x4){0.f, 0.f, 0.f, 0.f};
        f32x4 acc1 = (f32x4){0.f, 0.f, 0.f, 0.f};
#pragma unroll
        for (int kc = 0; kc < 8; ++kc) {
            short8 bw = *(const short8*)(WG + (size_t)((kc * 32 + ntile) * 64 + lane) * 8);
            float4 u0 = *(const float4*)(a0p + kc * 32);
            float4 u1 = *(const float4*)(a0p + kc * 32 + 4);
            float4 w0 = *(const float4*)(a1p + kc * 32);
            float4 w1 = *(const float4*)(a1p + kc * 32 + 4);
            short8 a0, a1;
            a0[0] = (short)f2bf(u0.x); a0[1] = (short)f2bf(u0.y); a0[2] = (short)f2bf(u0.z); a0[3] = (short)f2bf(u0.w);
            a0[4] = (short)f2bf(u1.x); a0[5] = (short)f2bf(u1.y); a0[6] = (short)f2bf(u1.z); a0[7] = (short)f2bf(u1.w);
            a1[0] = (short)f2bf(w0.x); a1[1] = (short)f2bf(w0.y); a1[2] = (short)f2bf(w0.z); a1[3] = (short)f2bf(w0.w);
            a1[4] = (short)f2bf(w1.x); a1[5] = (short)f2bf(w1.y); a1[6] = (short)f2bf(w1.z); a1[7] = (short)f2bf(w1.w);
            acc0 = __builtin_amdgcn_mfma_f32_16x16x32_bf16(a0, bw, acc0, 0, 0, 0);
            acc1 = __builtin_amdgcn_mfma_f32_16x16x32_bf16(a1, bw, acc1, 0, 0, 0);
        }
        float bv = ds_b[n0 + id];
#pragma unroll
        for (int mt = 0; mt < 2; ++mt) {
            f32x4 av = mt ? acc1 : acc0;
#pragma unroll
            for (int r = 0; r < 4; ++r) {
                int row = m0 + mt * 16 + quad * 4 + r;
                ATTV[(size_t)row * 512 + n0 + id] = av[r] + bv;
            }
        }
    }
    gridbar(BAR + 0);

    for (int l = 0; l < 2; ++l) {
        // ---------------- stage B: attn + LN1 (1 row per wave) ----------------
        {
            int gid = bid * 4 + wv;
            int b = gid >> 7, m = gid & 127;
            int lt = left[m], rt = right[m];
            int h = lane >> 3, d8 = lane & 7;
            const unsigned short* kb = KV + ((size_t)(l * 8 + h) << 20);
            const unsigned short* vb = KV + ((size_t)(16 + l * 8 + h) << 20);
            const float* g1 = ln1_g + l * 512;
            const float* bb1 = ln1_b + l * 512;
            float av8[8], att8[8];
            {
                const float* avp = ATTV + (size_t)gid * 512 + lane * 8;
                float4 u0 = *(const float4*)(avp);
                float4 u1 = *(const float4*)(avp + 4);
                av8[0] = u0.x; av8[1] = u0.y; av8[2] = u0.z; av8[3] = u0.w;
                av8[4] = u1.x; av8[5] = u1.y; av8[6] = u1.z; av8[7] = u1.w;
            }
#pragma unroll
            for (int j = 0; j < 8; ++j) att8[j] = 0.f;
#pragma unroll 2
            for (int s = 0; s < 8; ++s) {
                int t1 = (s < iv) ? m : rt;
                size_t o0 = (size_t)((b * 8 + s) * 256 + lt) * 64 + d8 * 8;
                size_t o1 = (size_t)((b * 8 + s) * 256 + t1) * 64 + d8 * 8;
                uint4 k0u = *(const uint4*)(kb + o0);
                uint4 k1u = *(const uint4*)(kb + o1);
                uint4 v0u = *(const uint4*)(vb + o0);
                uint4 v1u = *(const uint4*)(vb + o1);
                const unsigned short* k0 = (const unsigned short*)&k0u;
                const unsigned short* k1 = (const unsigned short*)&k1u;
                const unsigned short* v0 = (const unsigned short*)&v0u;
                const unsigned short* v1 = (const unsigned short*)&v1u;
                float p0 = 0.f, p1 = 0.f;
#pragma unroll
                for (int j = 0; j < 8; ++j) {
                    p0 += av8[j] * bf2f(k0[j]);
                    p1 += av8[j] * bf2f(k1[j]);
                }
#pragma unroll
                for (int o = 1; o < 8; o <<= 1) {
                    p0 += __shfl_xor(p0, o, 64);
                    p1 += __shfl_xor(p1, o, 64);
                }
                p0 *= 0.125f; p1 *= 0.125f;
                float mx = fmaxf(p0, p1);
                float e0 = __expf(p0 - mx), e1 = __expf(p1 - mx);
                float inv = 1.f / (e0 + e1);
                float w0 = e0 * inv, w1 = e1 * inv;
#pragma unroll
                for (int j = 0; j < 8; ++j)
                    att8[j] += w0 * bf2f(v0[j]) + w1 * bf2f(v1[j]);
            }
            float x8[8], sum = 0.f;
#pragma unroll
            for (int j = 0; j < 8; ++j) { x8[j] = av8[j] + att8[j]; sum += x8[j]; }
            float mu = wred(sum) * (1.f / 512.f);
            float s2 = 0.f;
#pragma unroll
            for (int j = 0; j < 8; ++j) { float d = x8[j] - mu; s2 += d * d; }
            float rs = rsqrtf(wred(s2) * (1.f / 512.f) + 1e-5f);
            const float* gp = g1 + lane * 8;
            const float* bp = bb1 + lane * 8;
            float* of = XBUF + (size_t)gid * 512 + lane * 8;
            unsigned short* ob = XBUFB + (size_t)gid * 512 + lane * 8;
            __align__(16) float vout[8];
            __align__(16) unsigned short pb[8];
#pragma unroll
            for (int j = 0; j < 8; ++j) {
                float v = (x8[j] - mu) * rs * gp[j] + bp[j];
                vout[j] = v; pb[j] = f2bf(v);
            }
            *(float4*)(of) = *(float4*)vout;
            *(float4*)(of + 4) = *(float4*)(vout + 4);
            *(uint4*)(ob) = *(uint4*)pb;
        }
        gridbar(BAR + 1 + l * 4);

        // ---------------- stage C: FF1 ----------------
        gemm_stage(XBUFB, WG + 131072 + (size_t)l * 262144, ffb1 + l * 512,
                   nullptr, nullptr, FBUFB, 512, 512, 1, bid & 7, bid >> 3);
        gridbar(BAR + 2 + l * 4);

        // ---------------- stage D: FF2 + residual ----------------
        gemm_stage(FBUFB, WG + 655360 + (size_t)l * 262144, ffb2 + l * 512,
                   XBUF, YBUF, nullptr, 512, 512, 0, bid & 7, bid >> 3);
        gridbar(BAR + 3 + l * 4);

        // ---------------- stage E: LN2 ----------------
        {
            int gid = bid * 4 + wv;
            const float* g2 = ln2_g + l * 512;
            const float* bb2 = ln2_b + l * 512;
            float x8[8], sum = 0.f;
            {
                const float* ipt = YBUF + (size_t)gid * 512 + lane * 8;
                float4 u0 = *(const float4*)(ipt);
                float4 u1 = *(const float4*)(ipt + 4);
                x8[0] = u0.x; x8[1] = u0.y; x8[2] = u0.z; x8[3] = u0.w;
                x8[4] = u1.x; x8[5] = u1.y; x8[6] = u1.z; x8[7] = u1.w;
            }
#pragma unroll
            for (int j = 0; j < 8; ++j) sum += x8[j];
            float mu = wred(sum) * (1.f / 512.f);
            float s2 = 0.f;
#pragma unroll
            for (int j = 0; j < 8; ++j) { float d = x8[j] - mu; s2 += d * d; }
            float rs = rsqrtf(wred(s2) * (1.f / 512.f) + 1e-5f);
            const float* gp = g2 + lane * 8;
            const float* bp = bb2 + lane * 8;
            float* of = ATTV + (size_t)gid * 512 + lane * 8;
            unsigned short* ob = ATTVB + (size_t)gid * 512 + lane * 8;
            __align__(16) float vout[8];
            __align__(16) unsigned short pb[8];
#pragma unroll
            for (int j = 0; j < 8; ++j) {
                float v = (x8[j] - mu) * rs * gp[j] + bp[j];
                vout[j] = v; pb[j] = f2bf(v);
            }
            *(float4*)(of) = *(float4*)vout;
            *(float4*)(of + 4) = *(float4*)(vout + 4);
            *(uint4*)(ob) = *(uint4*)pb;
        }
        gridbar(BAR + 4 + l * 4);
    }

    // ---------------- stage F: de1 (N=256, K=512, relu) ----------------
    if (bid < 128)
        gemm_stage(ATTVB, WG + 1179648, deb1, nullptr, nullptr, XBUFB,
                   512, 256, 1, bid & 3, bid >> 2);
    gridbar(BAR + 9);
    // ---------------- stage G: de2 (N=256, K=256, relu) ----------------
    if (bid < 128)
        gemm_stage(XBUFB, WG + 1310720, deb2, nullptr, nullptr, FBUFB,
                   256, 256, 1, bid & 3, bid >> 2);
    gridbar(BAR + 10);
    // ---------------- stage H: de3 (N=512, K=256) -> out ----------------
    gemm_stage(FBUFB, WG + 1376256, deb3, nullptr, out, nullptr,
               256, 512, 0, bid & 7, bid >> 3);
}

// ---------------------------------------------------------------------------
extern "C" void kernel_launch(void* const* d_in, const int* in_sizes, int n_in,
                              void* d_out, int out_size, void* d_ws, size_t ws_size,
                              hipStream_t stream) {
    const float* encoded = (const float*)d_in[0];
    const float* true_u  = (const float*)d_in[1];
    const int* mid_idx   = (const int*)d_in[2];
    const int* left_idx  = (const int*)d_in[3];
    const int* right_idx = (const int*)d_in[4];
    const int* ip        = (const int*)d_in[5];
    const float* ds_W = (const float*)d_in[6];
    const float* ds_b = (const float*)d_in[7];
    const float* kW1 = (const float*)d_in[8];
    const float* kb1 = (const float*)d_in[9];
    const float* kW2 = (const float*)d_in[10];
    const float* kb2 = (const float*)d_in[11];
    const float* kW3 = (const float*)d_in[12];
    const float* kb3 = (const float*)d_in[13];
    const float* vW1 = (const float*)d_in[14];
    const float* vb1 = (const float*)d_in[15];
    const float* vW2 = (const float*)d_in[16];
    const float* vb2 = (const float*)d_in[17];
    const float* vW3 = (const float*)d_in[18];
    const float* vb3 = (const float*)d_in[19];
    const float* ln1_g = (const float*)d_in[20];
    const float* ln1_b = (const float*)d_in[21];
    const float* ln2_g = (const float*)d_in[22];
    const float* ln2_b = (const float*)d_in[23];
    const float* ffW1 = (const float*)d_in[24];
    const float* ffb1 = (const float*)d_in[25];
    const float* ffW2 = (const float*)d_in[26];
    const float* ffb2 = (const float*)d_in[27];
    const float* deW1 = (const float*)d_in[28];
    const float* deb1 = (const float*)d_in[29];
    const float* deW2 = (const float*)d_in[30];
    const float* deb2 = (const float*)d_in[31];
    const float* deW3 = (const float*)d_in[32];
    const float* deb3 = (const float*)d_in[33];

    char* ws = (char*)d_ws;
    unsigned short* XF    = (unsigned short*)(ws + 0);          //  8,388,608
    unsigned short* WP    = (unsigned short*)(ws + 8388608);    //  9,437,184
    float* W1L            = (float*)(ws + 17825792);            //     32,768
    unsigned short* KV    = (unsigned short*)(ws + 17858560);   // 67,108,864
    unsigned short* WG    = (unsigned short*)(ws + 84967424);   //  3,014,656
    float* ATTV           = (float*)(ws + 87982080);            //  2,097,152
    float* XBUF           = (float*)(ws + 90079232);            //  2,097,152
    float* YBUF           = (float*)(ws + 92176384);            //  2,097,152
    unsigned short* ATTVB = (unsigned short*)(ws + 94273536);   //  1,048,576
    unsigned short* XBUFB = (unsigned short*)(ws + 95322112);   //  1,048,576
    unsigned short* FBUFB = (unsigned short*)(ws + 96370688);   //  1,048,576
    unsigned* BAR         = (unsigned*)(ws + 97419264);         //         64

    prep_all<<<1648, 256, 0, stream>>>(encoded, kW1, kW2, kW3, vW1, vW2, vW3,
                                       ds_W, ffW1, ffW2, deW1, deW2, deW3,
                                       XF, WP, W1L, WG, BAR);
    heads_mlp<<<8192, 256, 0, stream>>>(true_u, XF, WP, W1L, kb1, kb2, kb3,
                                        vb1, vb2, vb3, KV);
    tail_fused<<<256, 256, 0, stream>>>(encoded, mid_idx, left_idx, right_idx, ip,
                                        KV, WG, ds_b, ln1_g, ln1_b, ln2_g, ln2_b,
                                        ffb1, ffb2, deb1, deb2, deb3,
                                        ATTV, XBUF, YBUF, ATTVB, XBUFB, FBUFB,
                                        (float*)d_out, BAR);
}

// Round 9
// 429.476 us; speedup vs baseline: 1.3532x; 1.3532x over previous
//
#include <hip/hip_runtime.h>
#include <hip/hip_bf16.h>

// Problem constants
#define NB 8
#define NS 8
#define NT 256
#define ND 256
#define NH 8
#define NDK 64
#define NHD 512
#define NL 2
#define NF 256
#define NR 512
#define NM 128
#define NTOK 16384   // B*S*T
#define NROW 1024    // B*M

typedef __attribute__((ext_vector_type(8))) short short8;
typedef __attribute__((ext_vector_type(4))) float f32x4;

__device__ __forceinline__ unsigned short f2bf(float x) {
    unsigned u = __builtin_bit_cast(unsigned, x);
    unsigned r = (u + 0x7fffu + ((u >> 16) & 1u)) >> 16;
    return (unsigned short)r;
}
__device__ __forceinline__ float bf2f(unsigned short x) {
    return __builtin_bit_cast(float, ((unsigned)x) << 16);
}
__device__ __forceinline__ float wred(float v) {
#pragma unroll
    for (int o = 32; o > 0; o >>= 1) v += __shfl_xor(v, o, 64);
    return v;
}

// ---------------------------------------------------------------------------
// Merged prep kernel.  Grid 1648 blocks:
//  [0,512):    encoded fp32 -> XF bf16 fragment-major (32-token LDS transpose)
//  [512,1280): head weights -> WP fragment-major images + W1L
//  [1280,1648): ds/ff/de weights -> WG fragment-major images (B-orientation)
// ---------------------------------------------------------------------------
__global__ __launch_bounds__(256) void prep_all(
    const float* __restrict__ enc,
    const float* __restrict__ kW1, const float* __restrict__ kW2, const float* __restrict__ kW3,
    const float* __restrict__ vW1, const float* __restrict__ vW2, const float* __restrict__ vW3,
    const float* __restrict__ dsW, const float* __restrict__ ffW1,
    const float* __restrict__ ffW2, const float* __restrict__ deW1,
    const float* __restrict__ deW2, const float* __restrict__ deW3,
    unsigned short* __restrict__ XF, unsigned short* __restrict__ WP,
    float* __restrict__ W1L, unsigned short* __restrict__ WG) {
    __shared__ float T[32][257];
    int bid = blockIdx.x, tid = threadIdx.x;
    if (bid < 512) {
        int t0 = bid * 32;
        const float* src = enc + (size_t)t0 * 256;
#pragma unroll
        for (int it = 0; it < 8; ++it) {
            int f4 = it * 256 + tid;
            int row = f4 >> 6, c = (f4 & 63) * 4;
            float4 v = *(const float4*)(src + row * 256 + c);
            T[row][c] = v.x; T[row][c + 1] = v.y; T[row][c + 2] = v.z; T[row][c + 3] = v.w;
        }
        __syncthreads();
        int tile = t0 >> 7, g = (t0 >> 6) & 1, nt0 = (t0 >> 4) & 3;
#pragma unroll
        for (int i = 0; i < 32; i += 8) {
            int o = tid * 32 + i;
            int lane = (o >> 3) & 63, ntp = (o >> 9) & 1, kc = o >> 10;
            int id = lane & 15, quad = lane >> 4;
            __align__(16) unsigned short p[8];
#pragma unroll
            for (int j = 0; j < 8; ++j) p[j] = f2bf(T[ntp * 16 + id][kc * 32 + quad * 8 + j]);
            size_t dsto = ((size_t)((((tile * 8 + kc) * 2 + g) * 4 + (nt0 + ntp)) * 64 + lane)) * 8;
            *(uint4*)(XF + dsto) = *(uint4*)p;
        }
    } else if (bid < 1280) {
        int lb = bid - 512;
        int combo = lb / 24, r = lb % 24;
        int st = r >> 3, kc = r & 7;
        int kvv = combo >> 4, l = (combo >> 3) & 1, h = combo & 7;
        unsigned short* dstc = WP + (size_t)combo * 147456;
        if (st < 2) {
            const float* W = (st == 0) ? (kvv ? vW1 : kW1) : (kvv ? vW2 : kW2);
            int rows = (st == 0) ? 257 : 256;
            const float* src = W + ((size_t)(l * 8 + h) * rows + kc * 32) * 256;
#pragma unroll
            for (int it = 0; it < 8; ++it) {
                int f4 = it * 256 + tid;
                int row = f4 >> 6, c = (f4 & 63) * 4;
                float4 v = *(const float4*)(src + (size_t)row * 256 + c);
                T[row][c] = v.x; T[row][c + 1] = v.y; T[row][c + 2] = v.z; T[row][c + 3] = v.w;
            }
            __syncthreads();
            unsigned short* dst = dstc + st * 65536 + kc * 8192;
#pragma unroll
            for (int i = 0; i < 32; i += 8) {
                int o = tid * 32 + i;
                int lane = (o >> 3) & 63, ftile = o >> 9;
                int id = lane & 15, quad = lane >> 4;
                __align__(16) unsigned short p[8];
#pragma unroll
                for (int j = 0; j < 8; ++j) p[j] = f2bf(T[quad * 8 + j][ftile * 16 + id]);
                *(uint4*)(dst + o) = *(uint4*)p;
            }
            if (st == 0 && kc == 0) {
                const float* hw = (kvv ? vW1 : kW1) + (size_t)(l * 8 + h) * 257 * 256;
                W1L[combo * 256 + tid] = hw[65536 + tid];
            }
        } else {
            const float* src = (kvv ? vW3 : kW3) + ((size_t)(l * 8 + h) * 256 + kc * 32) * 64;
#pragma unroll
            for (int it = 0; it < 2; ++it) {
                int f4 = it * 256 + tid;
                int row = f4 >> 4, c = (f4 & 15) * 4;
                float4 v = *(const float4*)(src + (size_t)row * 64 + c);
                T[row][c] = v.x; T[row][c + 1] = v.y; T[row][c + 2] = v.z; T[row][c + 3] = v.w;
            }
            __syncthreads();
            unsigned short* dst = dstc + 131072 + kc * 2048;
            int o = tid * 8;
            int lane = tid & 63, ftile = tid >> 6;
            int id = lane & 15, quad = lane >> 4;
            __align__(16) unsigned short p[8];
#pragma unroll
            for (int j = 0; j < 8; ++j) p[j] = f2bf(T[quad * 8 + j][ftile * 16 + id]);
            *(uint4*)(dst + o) = *(uint4*)p;
        }
    } else {
        int lb0 = bid - 1280;
        const float* src; int N, kc, ng; size_t base;
        if (lb0 < 32)       { int lb = lb0;       src = dsW;           N = 512; base = 0;       kc = lb >> 2; ng = lb & 3; }
        else if (lb0 < 96)  { int lb = lb0 - 32;  src = ffW1;          N = 512; base = 131072;  kc = lb >> 2; ng = lb & 3; }
        else if (lb0 < 160) { int lb = lb0 - 96;  src = ffW1 + 262144; N = 512; base = 393216;  kc = lb >> 2; ng = lb & 3; }
        else if (lb0 < 224) { int lb = lb0 - 160; src = ffW2;          N = 512; base = 655360;  kc = lb >> 2; ng = lb & 3; }
        else if (lb0 < 288) { int lb = lb0 - 224; src = ffW2 + 262144; N = 512; base = 917504;  kc = lb >> 2; ng = lb & 3; }
        else if (lb0 < 320) { int lb = lb0 - 288; src = deW1;          N = 256; base = 1179648; kc = lb >> 1; ng = lb & 1; }
        else if (lb0 < 336) { int lb = lb0 - 320; src = deW2;          N = 256; base = 1310720; kc = lb >> 1; ng = lb & 1; }
        else                { int lb = lb0 - 336; src = deW3;          N = 512; base = 1376256; kc = lb >> 2; ng = lb & 3; }
        int NTl = N >> 4;
        const float* s = src + (size_t)(kc * 32) * N + ng * 128;
#pragma unroll
        for (int it = 0; it < 4; ++it) {
            int f4 = it * 256 + tid;
            int row = f4 >> 5, c = (f4 & 31) * 4;
            float4 v = *(const float4*)(s + (size_t)row * N + c);
            T[row][c] = v.x; T[row][c + 1] = v.y; T[row][c + 2] = v.z; T[row][c + 3] = v.w;
        }
        __syncthreads();
        unsigned short* d = WG + base + (size_t)(kc * NTl + ng * 8) * 512;
#pragma unroll
        for (int i = 0; i < 16; i += 8) {
            int o = tid * 16 + i;
            int lane = (o >> 3) & 63, ntl = o >> 9;
            int id = lane & 15, quad = lane >> 4;
            __align__(16) unsigned short p[8];
#pragma unroll
            for (int j = 0; j < 8; ++j) p[j] = f2bf(T[quad * 8 + j][ntl * 16 + id]);
            *(uint4*)(d + o) = *(uint4*)p;
        }
    }
}

// ---------------------------------------------------------------------------
// Fused per-head MLP v7 (unchanged): tile-major grid, combo-major KV,
// 2-deep W prefetch, 64-token tiles, 4 blocks/CU.
// ---------------------------------------------------------------------------
__global__ __launch_bounds__(256, 4) void heads_mlp(
    const float* __restrict__ tu, const unsigned short* __restrict__ XF,
    const unsigned short* __restrict__ WP, const float* __restrict__ W1L,
    const float* __restrict__ kb1, const float* __restrict__ kb2, const float* __restrict__ kb3,
    const float* __restrict__ vb1, const float* __restrict__ vb2, const float* __restrict__ vb3,
    unsigned short* __restrict__ KV) {
    __shared__ __align__(16) unsigned short smem[16896];   // 33792 B

    const int tid = threadIdx.x;
    const int w2 = tid >> 6, lane = tid & 63, id = lane & 15, quad = lane >> 4;
    const int combo = blockIdx.x & 31, t64 = blockIdx.x >> 5;
    const int kvv = combo >> 4, l = (combo >> 3) & 1, h = combo & 7;
    const int r0 = t64 * 64;
    const int tile128 = t64 >> 1, g = t64 & 1;
    const unsigned short* WF1 = WP + (size_t)combo * 147456;
    const unsigned short* WF2 = WF1 + 65536;
    const unsigned short* WF3 = WF1 + 131072;
    const float* b1 = (kvv ? vb1 : kb1) + (l * 8 + h) * 256;
    const float* b2 = (kvv ? vb2 : kb2) + (l * 8 + h) * 256;
    const float* b3 = (kvv ? vb3 : kb3) + (l * 8 + h) * 64;

    short8 afb[2][4];
#pragma unroll
    for (int ft = 0; ft < 4; ++ft) {
        afb[0][ft] = *(const short8*)(WF1 + (size_t)((w2 * 4 + ft) * 64 + lane) * 8);
        afb[1][ft] = *(const short8*)(WF1 + (size_t)((16 + w2 * 4 + ft) * 64 + lane) * 8);
    }
    {
        const uint4* s = (const uint4*)(XF + (size_t)tile128 * 32768 + g * 2048);
        uint4* d = (uint4*)smem;
#pragma unroll
        for (int kc = 0; kc < 8; ++kc) d[kc * 256 + tid] = s[kc * 512 + tid];
    }
    __syncthreads();

    f32x4 acc[4][4];
#pragma unroll
    for (int i = 0; i < 4; ++i)
#pragma unroll
        for (int j = 0; j < 4; ++j) acc[i][j] = (f32x4){0.f, 0.f, 0.f, 0.f};

    // stage 1
    {
#pragma unroll
        for (int kc = 0; kc < 8; ++kc) {
            short8 tn[4];
            if (kc + 2 < 8) {
#pragma unroll
                for (int ft = 0; ft < 4; ++ft)
                    tn[ft] = *(const short8*)(WF1 + (size_t)(((kc + 2) * 16 + w2 * 4 + ft) * 64 + lane) * 8);
            }
            short8 bf[4];
#pragma unroll
            for (int nt = 0; nt < 4; ++nt)
                bf[nt] = *(const short8*)(smem + (size_t)(kc * 4 + nt) * 512 + lane * 8);
#pragma unroll
            for (int ft = 0; ft < 4; ++ft)
#pragma unroll
                for (int nt = 0; nt < 4; ++nt)
                    acc[ft][nt] = __builtin_amdgcn_mfma_f32_16x16x32_bf16(afb[kc & 1][ft], bf[nt], acc[ft][nt], 0, 0, 0);
            if (kc + 2 < 8) {
#pragma unroll
                for (int ft = 0; ft < 4; ++ft) afb[kc & 1][ft] = tn[ft];
            }
        }
    }
    __syncthreads();
    {
        float ur[4];
#pragma unroll
        for (int nt = 0; nt < 4; ++nt) ur[nt] = tu[r0 + nt * 16 + id];
#pragma unroll
        for (int ft = 0; ft < 4; ++ft) {
            int fb = w2 * 64 + ft * 16 + quad * 4;
            float4 bb = *(const float4*)(b1 + fb);
            float4 wl = *(const float4*)(W1L + combo * 256 + fb);
            const float* bbp = (const float*)&bb;
            const float* wlp = (const float*)&wl;
#pragma unroll
            for (int nt = 0; nt < 4; ++nt) {
                unsigned short p[4];
#pragma unroll
                for (int r = 0; r < 4; ++r) {
                    float v = acc[ft][nt][r] + bbp[r] + ur[nt] * wlp[r];
                    p[r] = f2bf(fmaxf(v, 0.f));
                }
                uint2 pk;
                pk.x = (unsigned)p[0] | ((unsigned)p[1] << 16);
                pk.y = (unsigned)p[2] | ((unsigned)p[3] << 16);
                *(uint2*)(smem + (size_t)(nt * 16 + id) * 264 + fb) = pk;
            }
        }
    }
    __syncthreads();

    // stage 2
#pragma unroll
    for (int i = 0; i < 4; ++i)
#pragma unroll
        for (int j = 0; j < 4; ++j) acc[i][j] = (f32x4){0.f, 0.f, 0.f, 0.f};
    {
#pragma unroll
        for (int ft = 0; ft < 4; ++ft) {
            afb[0][ft] = *(const short8*)(WF2 + (size_t)((w2 * 4 + ft) * 64 + lane) * 8);
            afb[1][ft] = *(const short8*)(WF2 + (size_t)((16 + w2 * 4 + ft) * 64 + lane) * 8);
        }
#pragma unroll
        for (int kc = 0; kc < 8; ++kc) {
            short8 tn[4];
            if (kc + 2 < 8) {
#pragma unroll
                for (int ft = 0; ft < 4; ++ft)
                    tn[ft] = *(const short8*)(WF2 + (size_t)(((kc + 2) * 16 + w2 * 4 + ft) * 64 + lane) * 8);
            }
            short8 bf[4];
#pragma unroll
            for (int nt = 0; nt < 4; ++nt)
                bf[nt] = *(const short8*)(smem + (size_t)(nt * 16 + id) * 264 + kc * 32 + quad * 8);
#pragma unroll
            for (int ft = 0; ft < 4; ++ft)
#pragma unroll
                for (int nt = 0; nt < 4; ++nt)
                    acc[ft][nt] = __builtin_amdgcn_mfma_f32_16x16x32_bf16(afb[kc & 1][ft], bf[nt], acc[ft][nt], 0, 0, 0);
            if (kc + 2 < 8) {
#pragma unroll
                for (int ft = 0; ft < 4; ++ft) afb[kc & 1][ft] = tn[ft];
            }
        }
    }
    __syncthreads();
#pragma unroll
    for (int ft = 0; ft < 4; ++ft) {
        int fb = w2 * 64 + ft * 16 + quad * 4;
        float4 bb = *(const float4*)(b2 + fb);
        const float* bbp = (const float*)&bb;
#pragma unroll
        for (int nt = 0; nt < 4; ++nt) {
            unsigned short p[4];
#pragma unroll
            for (int r = 0; r < 4; ++r)
                p[r] = f2bf(fmaxf(acc[ft][nt][r] + bbp[r], 0.f));
            uint2 pk;
            pk.x = (unsigned)p[0] | ((unsigned)p[1] << 16);
            pk.y = (unsigned)p[2] | ((unsigned)p[3] << 16);
            *(uint2*)(smem + (size_t)(nt * 16 + id) * 264 + fb) = pk;
        }
    }
    __syncthreads();

    // stage 3
    f32x4 a3[4];
#pragma unroll
    for (int i = 0; i < 4; ++i) a3[i] = (f32x4){0.f, 0.f, 0.f, 0.f};
    {
        short8 af3[4], af3n[4];
#pragma unroll
        for (int ft = 0; ft < 4; ++ft)
            af3[ft] = *(const short8*)(WF3 + (size_t)(ft * 64 + lane) * 8);
#pragma unroll
        for (int kc = 0; kc < 8; ++kc) {
            if (kc < 7) {
#pragma unroll
                for (int ft = 0; ft < 4; ++ft)
                    af3n[ft] = *(const short8*)(WF3 + (size_t)(((kc + 1) * 4 + ft) * 64 + lane) * 8);
            }
            short8 b3f = *(const short8*)(smem + (size_t)(w2 * 16 + id) * 264 + kc * 32 + quad * 8);
#pragma unroll
            for (int ft = 0; ft < 4; ++ft)
                a3[ft] = __builtin_amdgcn_mfma_f32_16x16x32_bf16(af3[ft], b3f, a3[ft], 0, 0, 0);
#pragma unroll
            for (int ft = 0; ft < 4; ++ft) af3[ft] = af3n[ft];
        }
    }
    __syncthreads();
    {
        int tl = w2 * 16 + id;
#pragma unroll
        for (int ft = 0; ft < 4; ++ft) {
            int dk0 = ft * 16 + quad * 4;
            float4 bb = *(const float4*)(b3 + dk0);
            const float* bbp = (const float*)&bb;
            unsigned short p[4];
#pragma unroll
            for (int r = 0; r < 4; ++r) p[r] = f2bf(a3[ft][r] + bbp[r]);
            uint2 pk;
            pk.x = (unsigned)p[0] | ((unsigned)p[1] << 16);
            pk.y = (unsigned)p[2] | ((unsigned)p[3] << 16);
            *(uint2*)(smem + (size_t)tl * 72 + dk0) = pk;
        }
    }
    __syncthreads();
    {
#pragma unroll
        for (int it = 0; it < 2; ++it) {
            int tl = it * 32 + (tid >> 3), part = tid & 7;
            uint4 v = *(const uint4*)(smem + (size_t)tl * 72 + part * 8);
            size_t base = ((size_t)combo << 20) + (size_t)(r0 + tl) * 64 + part * 8;
            *(uint4*)(KV + base) = v;
        }
    }
}

// ---------------------------------------------------------------------------
// ds gemm with fused gather, wave = 1 ntile x 1 mtile (16 rows).
// grid (8, 64), block 256.
// ---------------------------------------------------------------------------
__global__ __launch_bounds__(256) void gemm_ds(
    const float* __restrict__ enc, const int* __restrict__ mid,
    const int* __restrict__ ip, const unsigned short* __restrict__ WF,
    const float* __restrict__ bias, float* __restrict__ outf) {
    int tid = threadIdx.x, wv = tid >> 6, lane = tid & 63;
    int id = lane & 15, quad = lane >> 4;
    int ntile = blockIdx.x * 4 + wv;
    int n0 = ntile * 16, m0 = blockIdx.y * 16;
    int iv = ip[0];
    int r0 = m0 + id;
    const float* a0p = enc + (((size_t)((r0 >> 7) * 8 + iv)) * 256 + mid[r0 & 127]) * 256 + quad * 8;
    f32x4 acc0 = (f32x4){0.f, 0.f, 0.f, 0.f};
#pragma unroll
    for (int kc = 0; kc < 8; ++kc) {
        short8 bw = *(const short8*)(WF + (size_t)((kc * 32 + ntile) * 64 + lane) * 8);
        float4 u0 = *(const float4*)(a0p + kc * 32);
        float4 u1 = *(const float4*)(a0p + kc * 32 + 4);
        short8 a0;
        a0[0] = (short)f2bf(u0.x); a0[1] = (short)f2bf(u0.y); a0[2] = (short)f2bf(u0.z); a0[3] = (short)f2bf(u0.w);
        a0[4] = (short)f2bf(u1.x); a0[5] = (short)f2bf(u1.y); a0[6] = (short)f2bf(u1.z); a0[7] = (short)f2bf(u1.w);
        acc0 = __builtin_amdgcn_mfma_f32_16x16x32_bf16(a0, bw, acc0, 0, 0, 0);
    }
    float bv = bias[n0 + id];
#pragma unroll
    for (int r = 0; r < 4; ++r) {
        int row = m0 + quad * 4 + r;
        outf[(size_t)row * 512 + n0 + id] = acc0[r] + bv;
    }
}

// ---------------------------------------------------------------------------
// bf16 MFMA gemm, wave = 1 ntile x 1 mtile (16 rows), 1-deep prefetch.
// grid (N/64, 64), block 256.
// out = [relu](A[1024xK]bf16 @ W[KxN]bf16 + bias [+ res_f32])
// ---------------------------------------------------------------------------
__global__ __launch_bounds__(256) void gemm_bf16(
    const unsigned short* __restrict__ A, const unsigned short* __restrict__ WF,
    const float* __restrict__ bias, const float* __restrict__ res,
    float* __restrict__ outf, unsigned short* __restrict__ outb,
    int K, int N, int relu) {
    int tid = threadIdx.x, wv = tid >> 6, lane = tid & 63;
    int id = lane & 15, quad = lane >> 4;
    int ntile = blockIdx.x * 4 + wv;
    int n0 = ntile * 16, m0 = blockIdx.y * 16;
    int NTl = N >> 4, KC = K >> 5;
    f32x4 acc0 = (f32x4){0.f, 0.f, 0.f, 0.f};
    short8 bw = *(const short8*)(WF + (size_t)(ntile * 64 + lane) * 8);
    short8 a0 = *(const short8*)(A + (size_t)(m0 + id) * K + quad * 8);
    for (int kc = 0; kc < KC; ++kc) {
        short8 bwn, a0n;
        if (kc + 1 < KC) {
            bwn = *(const short8*)(WF + (size_t)(((kc + 1) * NTl + ntile) * 64 + lane) * 8);
            a0n = *(const short8*)(A + (size_t)(m0 + id) * K + (kc + 1) * 32 + quad * 8);
        }
        acc0 = __builtin_amdgcn_mfma_f32_16x16x32_bf16(a0, bw, acc0, 0, 0, 0);
        bw = bwn; a0 = a0n;
    }
    float bv = bias[n0 + id];
#pragma unroll
    for (int r = 0; r < 4; ++r) {
        int row = m0 + quad * 4 + r;
        int n = n0 + id;
        float v = acc0[r] + bv;
        if (res) v += res[(size_t)row * N + n];
        if (relu) v = fmaxf(v, 0.f);
        if (outf) outf[(size_t)row * N + n] = v;
        if (outb) outb[(size_t)row * N + n] = f2bf(v);
    }
}

// ---------------------------------------------------------------------------
// Attention (2 neighbors, softmax over n, sum over s) + residual + LN1.
// One wave per (b,m) row; lane = (h = lane>>3, d8 = lane&7).  Combo-major KV.
// grid 256 x 256 thr.  fp32 out + bf16 out.
// ---------------------------------------------------------------------------
__global__ __launch_bounds__(256) void attn_ln(
    const float* __restrict__ attv, const unsigned short* __restrict__ KV,
    const int* __restrict__ left, const int* __restrict__ right,
    const int* __restrict__ ip,
    const float* __restrict__ g, const float* __restrict__ bb,
    float* __restrict__ xout, unsigned short* __restrict__ xoutb, int l) {
    int tid = threadIdx.x, wv = tid >> 6, lane = tid & 63;
    int gid = blockIdx.x * 4 + wv;  // 0..1023 = b*128+m
    int b = gid >> 7, m = gid & 127;
    int iv = ip[0];
    int lt = left[m], rt = right[m];
    int h = lane >> 3, d8 = lane & 7;
    const unsigned short* kb = KV + ((size_t)(l * 8 + h) << 20);
    const unsigned short* vb = KV + ((size_t)(16 + l * 8 + h) << 20);
    float av8[8], att8[8];
    {
        const float* avp = attv + (size_t)gid * 512 + lane * 8;
        float4 u0 = *(const float4*)(avp);
        float4 u1 = *(const float4*)(avp + 4);
        av8[0] = u0.x; av8[1] = u0.y; av8[2] = u0.z; av8[3] = u0.w;
        av8[4] = u1.x; av8[5] = u1.y; av8[6] = u1.z; av8[7] = u1.w;
    }
#pragma unroll
    for (int j = 0; j < 8; ++j) att8[j] = 0.f;
#pragma unroll 2
    for (int s = 0; s < 8; ++s) {
        int t1 = (s < iv) ? m : rt;
        size_t o0 = (size_t)((b * 8 + s) * 256 + lt) * 64 + d8 * 8;
        size_t o1 = (size_t)((b * 8 + s) * 256 + t1) * 64 + d8 * 8;
        uint4 k0u = *(const uint4*)(kb + o0);
        uint4 k1u = *(const uint4*)(kb + o1);
        uint4 v0u = *(const uint4*)(vb + o0);
        uint4 v1u = *(const uint4*)(vb + o1);
        const unsigned short* k0 = (const unsigned short*)&k0u;
        const unsigned short* k1 = (const unsigned short*)&k1u;
        const unsigned short* v0 = (const unsigned short*)&v0u;
        const unsigned short* v1 = (const unsigned short*)&v1u;
        float p0 = 0.f, p1 = 0.f;
#pragma unroll
        for (int j = 0; j < 8; ++j) {
            p0 += av8[j] * bf2f(k0[j]);
            p1 += av8[j] * bf2f(k1[j]);
        }
#pragma unroll
        for (int o = 1; o < 8; o <<= 1) {
            p0 += __shfl_xor(p0, o, 64);
            p1 += __shfl_xor(p1, o, 64);
        }
        p0 *= 0.125f; p1 *= 0.125f;
        float mx = fmaxf(p0, p1);
        float e0 = __expf(p0 - mx), e1 = __expf(p1 - mx);
        float inv = 1.f / (e0 + e1);
        float w0 = e0 * inv, w1 = e1 * inv;
#pragma unroll
        for (int j = 0; j < 8; ++j)
            att8[j] += w0 * bf2f(v0[j]) + w1 * bf2f(v1[j]);
    }
    float x8[8], sum = 0.f;
#pragma unroll
    for (int j = 0; j < 8; ++j) { x8[j] = av8[j] + att8[j]; sum += x8[j]; }
    float mu = wred(sum) * (1.f / 512.f);
    float s2 = 0.f;
#pragma unroll
    for (int j = 0; j < 8; ++j) { float d = x8[j] - mu; s2 += d * d; }
    float rs = rsqrtf(wred(s2) * (1.f / 512.f) + 1e-5f);
    {
        const float* gp = g + lane * 8;
        const float* bp = bb + lane * 8;
        float* of = xout + (size_t)gid * 512 + lane * 8;
        unsigned short* ob = xoutb + (size_t)gid * 512 + lane * 8;
        __align__(16) float vout[8];
        __align__(16) unsigned short pb[8];
#pragma unroll
        for (int j = 0; j < 8; ++j) {
            float v = (x8[j] - mu) * rs * gp[j] + bp[j];
            vout[j] = v; pb[j] = f2bf(v);
        }
        *(float4*)(of) = *(float4*)vout;
        *(float4*)(of + 4) = *(float4*)(vout + 4);
        *(uint4*)(ob) = *(uint4*)pb;
    }
}

// ---------------------------------------------------------------------------
// LayerNorm over 512, one wave per row, lane owns 8 contiguous cols.
// ---------------------------------------------------------------------------
__global__ __launch_bounds__(256) void ln_k(const float* __restrict__ in,
                                            const float* __restrict__ g,
                                            const float* __restrict__ bb,
                                            float* __restrict__ out,
                                            unsigned short* __restrict__ outb) {
    int tid = threadIdx.x, wv = tid >> 6, lane = tid & 63;
    int gid = blockIdx.x * 4 + wv;
    float x8[8], sum = 0.f;
    {
        const float* ip = in + (size_t)gid * 512 + lane * 8;
        float4 u0 = *(const float4*)(ip);
        float4 u1 = *(const float4*)(ip + 4);
        x8[0] = u0.x; x8[1] = u0.y; x8[2] = u0.z; x8[3] = u0.w;
        x8[4] = u1.x; x8[5] = u1.y; x8[6] = u1.z; x8[7] = u1.w;
    }
#pragma unroll
    for (int j = 0; j < 8; ++j) sum += x8[j];
    float mu = wred(sum) * (1.f / 512.f);
    float s2 = 0.f;
#pragma unroll
    for (int j = 0; j < 8; ++j) { float d = x8[j] - mu; s2 += d * d; }
    float rs = rsqrtf(wred(s2) * (1.f / 512.f) + 1e-5f);
    {
        const float* gp = g + lane * 8;
        const float* bp = bb + lane * 8;
        float* of = out + (size_t)gid * 512 + lane * 8;
        unsigned short* ob = outb + (size_t)gid * 512 + lane * 8;
        __align__(16) float vout[8];
        __align__(16) unsigned short pb[8];
#pragma unroll
        for (int j = 0; j < 8; ++j) {
            float v = (x8[j] - mu) * rs * gp[j] + bp[j];
            vout[j] = v; pb[j] = f2bf(v);
        }
        *(float4*)(of) = *(float4*)vout;
        *(float4*)(of + 4) = *(float4*)(vout + 4);
        *(uint4*)(ob) = *(uint4*)pb;
    }
}

// ---------------------------------------------------------------------------
extern "C" void kernel_launch(void* const* d_in, const int* in_sizes, int n_in,
                              void* d_out, int out_size, void* d_ws, size_t ws_size,
                              hipStream_t stream) {
    const float* encoded = (const float*)d_in[0];
    const float* true_u  = (const float*)d_in[1];
    const int* mid_idx   = (const int*)d_in[2];
    const int* left_idx  = (const int*)d_in[3];
    const int* right_idx = (const int*)d_in[4];
    const int* ip        = (const int*)d_in[5];
    const float* ds_W = (const float*)d_in[6];
    const float* ds_b = (const float*)d_in[7];
    const float* kW1 = (const float*)d_in[8];
    const float* kb1 = (const float*)d_in[9];
    const float* kW2 = (const float*)d_in[10];
    const float* kb2 = (const float*)d_in[11];
    const float* kW3 = (const float*)d_in[12];
    const float* kb3 = (const float*)d_in[13];
    const float* vW1 = (const float*)d_in[14];
    const float* vb1 = (const float*)d_in[15];
    const float* vW2 = (const float*)d_in[16];
    const float* vb2 = (const float*)d_in[17];
    const float* vW3 = (const float*)d_in[18];
    const float* vb3 = (const float*)d_in[19];
    const float* ln1_g = (const float*)d_in[20];
    const float* ln1_b = (const float*)d_in[21];
    const float* ln2_g = (const float*)d_in[22];
    const float* ln2_b = (const float*)d_in[23];
    const float* ffW1 = (const float*)d_in[24];
    const float* ffb1 = (const float*)d_in[25];
    const float* ffW2 = (const float*)d_in[26];
    const float* ffb2 = (const float*)d_in[27];
    const float* deW1 = (const float*)d_in[28];
    const float* deb1 = (const float*)d_in[29];
    const float* deW2 = (const float*)d_in[30];
    const float* deb2 = (const float*)d_in[31];
    const float* deW3 = (const float*)d_in[32];
    const float* deb3 = (const float*)d_in[33];

    char* ws = (char*)d_ws;
    unsigned short* XF    = (unsigned short*)(ws + 0);          //  8,388,608
    unsigned short* WP    = (unsigned short*)(ws + 8388608);    //  9,437,184
    float* W1L            = (float*)(ws + 17825792);            //     32,768
    unsigned short* KV    = (unsigned short*)(ws + 17858560);   // 67,108,864
    unsigned short* WG    = (unsigned short*)(ws + 84967424);   //  3,014,656
    float* ATTV           = (float*)(ws + 87982080);            //  2,097,152
    float* XBUF           = (float*)(ws + 90079232);            //  2,097,152
    float* YBUF           = (float*)(ws + 92176384);            //  2,097,152
    unsigned short* ATTVB = (unsigned short*)(ws + 94273536);   //  1,048,576
    unsigned short* XBUFB = (unsigned short*)(ws + 95322112);   //  1,048,576
    unsigned short* FBUFB = (unsigned short*)(ws + 96370688);   //  1,048,576 (end 97,419,264)
    unsigned short* DE1B = XBUFB;   // reuse (free after layers)
    unsigned short* DE2B = FBUFB;

    // WG image offsets (halves)
    unsigned short* WGds    = WG + 0;
    unsigned short* WGff1_0 = WG + 131072;
    unsigned short* WGff1_1 = WG + 393216;
    unsigned short* WGff2_0 = WG + 655360;
    unsigned short* WGff2_1 = WG + 917504;
    unsigned short* WGde1   = WG + 1179648;
    unsigned short* WGde2   = WG + 1310720;
    unsigned short* WGde3   = WG + 1376256;

    prep_all<<<1648, 256, 0, stream>>>(encoded, kW1, kW2, kW3, vW1, vW2, vW3,
                                       ds_W, ffW1, ffW2, deW1, deW2, deW3,
                                       XF, WP, W1L, WG);
    heads_mlp<<<8192, 256, 0, stream>>>(true_u, XF, WP, W1L, kb1, kb2, kb3,
                                        vb1, vb2, vb3, KV);
    gemm_ds<<<dim3(8, 64), 256, 0, stream>>>(encoded, mid_idx, ip, WGds, ds_b, ATTV);
    for (int l = 0; l < 2; ++l) {
        attn_ln<<<256, 256, 0, stream>>>(ATTV, KV, left_idx, right_idx, ip,
                                         ln1_g + l * 512, ln1_b + l * 512,
                                         XBUF, XBUFB, l);
        gemm_bf16<<<dim3(8, 64), 256, 0, stream>>>(XBUFB, (l ? WGff1_1 : WGff1_0),
                                                   ffb1 + l * 512, nullptr,
                                                   nullptr, FBUFB, 512, 512, 1);
        gemm_bf16<<<dim3(8, 64), 256, 0, stream>>>(FBUFB, (l ? WGff2_1 : WGff2_0),
                                                   ffb2 + l * 512, XBUF,
                                                   YBUF, nullptr, 512, 512, 0);
        ln_k<<<256, 256, 0, stream>>>(YBUF, ln2_g + l * 512, ln2_b + l * 512, ATTV, ATTVB);
    }
    gemm_bf16<<<dim3(4, 64), 256, 0, stream>>>(ATTVB, WGde1, deb1, nullptr,
                                               nullptr, DE1B, 512, 256, 1);
    gemm_bf16<<<dim3(4, 64), 256, 0, stream>>>(DE1B, WGde2, deb2, nullptr,
                                               nullptr, DE2B, 256, 256, 1);
    gemm_bf16<<<dim3(8, 64), 256, 0, stream>>>(DE2B, WGde3, deb3, nullptr,
                                               (float*)d_out, nullptr, 256, 512, 0);
}